// Round 3
// baseline (658.231 us; speedup 1.0000x reference)
//
#include <hip/hip_runtime.h>
#include <hip/hip_bf16.h>
#include <math.h>

typedef float v4f __attribute__((ext_vector_type(4)));

#define BATCH 4
#define NQ 4096
#define NK 4096
#define DIM 256
#define INNER 64
#define NEG_INF (-3.0e38f)

#define QT 32          // q rows per block
#define KC2 512        // k cols per chunk
#define HD 32          // dims per staged half-slab
#define SK 512         // khT row stride (no pad; XOR swizzle instead)
#define SQT 36         // qhT row stride

// ---------- K1: out[rows,64] = (X[rows,256] @ W[256,64]) * scale -------------
__global__ __launch_bounds__(256) void proj_kernel(
    const float* __restrict__ X, const float* __restrict__ W,
    float* __restrict__ out, float scale)
{
  __shared__ float xs[64 * 260];
  const int t = threadIdx.x;
  const int row0 = blockIdx.x * 64;

  #pragma unroll
  for (int it = 0; it < 16; ++it) {
    int idx = it * 256 + t;
    int r = idx >> 6, dq = idx & 63;
    v4f v = *reinterpret_cast<const v4f*>(X + (size_t)(row0 + r) * DIM + dq * 4);
    *reinterpret_cast<v4f*>(&xs[r * 260 + dq * 4]) = v;
  }
  __syncthreads();

  const int i0 = (t & 15) * 4;
  const int rg = t >> 4;
  float acc[4][4];
  #pragma unroll
  for (int p = 0; p < 4; ++p)
    #pragma unroll
    for (int i = 0; i < 4; ++i) acc[p][i] = 0.f;

  for (int d0 = 0; d0 < DIM; d0 += 4) {
    v4f w0 = *reinterpret_cast<const v4f*>(W + (d0 + 0) * INNER + i0);
    v4f w1 = *reinterpret_cast<const v4f*>(W + (d0 + 1) * INNER + i0);
    v4f w2 = *reinterpret_cast<const v4f*>(W + (d0 + 2) * INNER + i0);
    v4f w3 = *reinterpret_cast<const v4f*>(W + (d0 + 3) * INNER + i0);
    #pragma unroll
    for (int p = 0; p < 4; ++p) {
      v4f x = *reinterpret_cast<const v4f*>(&xs[(rg + 16 * p) * 260 + d0]);
      #pragma unroll
      for (int i = 0; i < 4; ++i) {
        float bs = x[0] * w0[i];
        bs = fmaf(x[1], w1[i], bs);
        bs = fmaf(x[2], w2[i], bs);
        bs = fmaf(x[3], w3[i], bs);
        acc[p][i] += bs;
      }
    }
  }
  #pragma unroll
  for (int p = 0; p < 4; ++p) {
    v4f o;
    #pragma unroll
    for (int i = 0; i < 4; ++i) o[i] = acc[p][i] * scale;
    *reinterpret_cast<v4f*>(out + (size_t)(row0 + rg + 16 * p) * INNER + i0) = o;
  }
}

// ---------- sorted top-5 branchless cascade insert (call only if x > v[4]) ---
__device__ __forceinline__ void insert5(float (&v)[5], int (&ix)[5], float x, int xi) {
  bool g0 = x > v[0], g1 = x > v[1], g2 = x > v[2], g3 = x > v[3];
  v[4]  = g3 ? v[3] : x;                 ix[4] = g3 ? ix[3] : xi;
  v[3]  = g3 ? (g2 ? v[2] : x) : v[3];   ix[3] = g3 ? (g2 ? ix[2] : xi) : ix[3];
  v[2]  = g2 ? (g1 ? v[1] : x) : v[2];   ix[2] = g2 ? (g1 ? ix[1] : xi) : ix[2];
  v[1]  = g1 ? (g0 ? v[0] : x) : v[1];   ix[1] = g1 ? (g0 ? ix[0] : xi) : ix[1];
  v[0]  = g0 ? x : v[0];                 ix[0] = g0 ? xi : ix[0];
}

// ---------- K2: fused scores + per-row top-5 ---------------------------------
// 256 thr = 4 waves; wave qg owns q rows qg*8..+7. Chunk = 512 k-cols staged
// as two 32-dim half-slabs khT[dd][512] (XOR col swizzle by dim-quad).
// Lane kg owns logical cols {4kg..4kg+3} and {256+4kg..+3}  (j=8, m=8).
__global__ __launch_bounds__(256, 2) void topk_kernel(
    const float* __restrict__ qh, const float* __restrict__ kh,
    float* __restrict__ topout)
{
  __shared__ float lds[HD * SK + 64 * SQT];   // 74752 B
  float* khT = lds;
  float* qhT = lds + HD * SK;

  const int t  = threadIdx.x;
  const int b  = blockIdx.x >> 7;
  const int q0 = (blockIdx.x & 127) * QT;
  const float* qb = qh + (size_t)b * NQ * INNER;
  const float* kb = kh + (size_t)b * NK * INNER;
  const int qg = t >> 6;                      // wave 0..3
  const int kg = t & 63;                      // lane

  // stage qhT[d][qc] once (transposed, stride 36)
  #pragma unroll
  for (int it = 0; it < 2; ++it) {
    int qc = it * 16 + (t & 15);
    int dg = t >> 4;
    v4f v = *reinterpret_cast<const v4f*>(qb + (size_t)(q0 + qc) * INNER + dg * 4);
    qhT[(dg * 4 + 0) * SQT + qc] = v[0];
    qhT[(dg * 4 + 1) * SQT + qc] = v[1];
    qhT[(dg * 4 + 2) * SQT + qc] = v[2];
    qhT[(dg * 4 + 3) * SQT + qc] = v[3];
  }

  float tv[8][5]; int ti[8][5];
  #pragma unroll
  for (int m = 0; m < 8; ++m)
    #pragma unroll
    for (int j = 0; j < 5; ++j) { tv[m][j] = NEG_INF; ti[m][j] = 0; }

  v4f accA[8], accB[8];

  for (int c = 0; c < NK / KC2; ++c) {
    #pragma unroll
    for (int h = 0; h < 2; ++h) {
      __syncthreads();                        // khT free to overwrite
      // ---- stage half-slab: dims h*32..h*32+31 for cols c*512..c*512+511 ----
      #pragma unroll
      for (int p = 0; p < 16; ++p) {
        int qid = p * 256 + t;
        int col = qid >> 3;                   // 0..511
        int dq  = qid & 7;                    // dim quad 0..7
        v4f v = *reinterpret_cast<const v4f*>(
            kb + (size_t)(c * KC2 + col) * INNER + h * HD + dq * 4);
        int pcol = col ^ (dq << 2);           // XOR swizzle (bits 2..4)
        khT[(dq * 4 + 0) * SK + pcol] = v[0];
        khT[(dq * 4 + 1) * SK + pcol] = v[1];
        khT[(dq * 4 + 2) * SK + pcol] = v[2];
        khT[(dq * 4 + 3) * SK + pcol] = v[3];
      }
      __syncthreads();

      if (h == 0) {
        #pragma unroll
        for (int m = 0; m < 8; ++m) {
          #pragma unroll
          for (int j = 0; j < 4; ++j) { accA[m][j] = 0.f; accB[m][j] = 0.f; }
        }
      }

      #pragma unroll 2
      for (int dd0 = 0; dd0 < HD; dd0 += 4) {
        const int x4 = dd0 & 0x1c;            // (dd0>>2)<<2 : swizzle bits
        const int pA = (4 * kg) ^ x4;
        const int gd = h * HD + dd0;
        v4f kA[4], kB[4], qa[4], qc4[4];
        #pragma unroll
        for (int s = 0; s < 4; ++s) {
          kA[s]  = *reinterpret_cast<const v4f*>(&khT[(dd0 + s) * SK + pA]);
          kB[s]  = *reinterpret_cast<const v4f*>(&khT[(dd0 + s) * SK + 256 + pA]);
          qa[s]  = *reinterpret_cast<const v4f*>(&qhT[(gd + s) * SQT + qg * 8]);
          qc4[s] = *reinterpret_cast<const v4f*>(&qhT[(gd + s) * SQT + qg * 8 + 4]);
        }
        #pragma unroll
        for (int m = 0; m < 8; ++m) {
          float q0v = (m < 4) ? qa[0][m & 3] : qc4[0][m & 3];
          float q1v = (m < 4) ? qa[1][m & 3] : qc4[1][m & 3];
          float q2v = (m < 4) ? qa[2][m & 3] : qc4[2][m & 3];
          float q3v = (m < 4) ? qa[3][m & 3] : qc4[3][m & 3];
          #pragma unroll
          for (int j = 0; j < 4; ++j) {
            float bsA = q0v * kA[0][j];        // same blocked order as round 2
            bsA = fmaf(q1v, kA[1][j], bsA);
            bsA = fmaf(q2v, kA[2][j], bsA);
            bsA = fmaf(q3v, kA[3][j], bsA);
            accA[m][j] += bsA;
            float bsB = q0v * kB[0][j];
            bsB = fmaf(q1v, kB[1][j], bsB);
            bsB = fmaf(q2v, kB[2][j], bsB);
            bsB = fmaf(q3v, kB[3][j], bsB);
            accB[m][j] += bsB;
          }
        }
      }
    }

    const int kbase = c * KC2 + 4 * kg;
    #pragma unroll
    for (int m = 0; m < 8; ++m) {
      float mxA = fmaxf(fmaxf(accA[m][0], accA[m][1]), fmaxf(accA[m][2], accA[m][3]));
      float mxB = fmaxf(fmaxf(accB[m][0], accB[m][1]), fmaxf(accB[m][2], accB[m][3]));
      if (fmaxf(mxA, mxB) > tv[m][4]) {
        #pragma unroll
        for (int j = 0; j < 4; ++j) {
          float xA = accA[m][j];
          if (xA > tv[m][4]) insert5(tv[m], ti[m], xA, kbase + j);
        }
        #pragma unroll
        for (int j = 0; j < 4; ++j) {
          float xB = accB[m][j];
          if (xB > tv[m][4]) insert5(tv[m], ti[m], xB, kbase + 256 + j);
        }
      }
    }
  }

  // full 64-lane butterfly merge; lane 0 of each wave ends with row results
  #pragma unroll
  for (int s = 1; s <= 32; s <<= 1) {
    #pragma unroll
    for (int m = 0; m < 8; ++m) {
      float bv[5]; int bi[5];
      #pragma unroll
      for (int j = 0; j < 5; ++j) {
        bv[j] = __shfl_xor(tv[m][j], s, 64);
        bi[j] = __shfl_xor(ti[m][j], s, 64);
      }
      #pragma unroll
      for (int j = 0; j < 5; ++j)
        if (bv[j] > tv[m][4]) insert5(tv[m], ti[m], bv[j], bi[j]);
    }
  }

  if (kg == 0) {
    #pragma unroll
    for (int m = 0; m < 8; ++m) {
      size_t rowg = (size_t)b * NQ + q0 + qg * 8 + m;
      #pragma unroll
      for (int j = 0; j < 5; ++j) {
        topout[rowg * 10 + j]     = tv[m][j];
        topout[rowg * 10 + 5 + j] = __int_as_float(ti[m][j]);
      }
    }
  }
}

// ---------- K3: fused zero-fill + softmax-of-survivors scatter (f32 out) -----
__global__ __launch_bounds__(256) void scatter_kernel(
    const float* __restrict__ topv, float* __restrict__ out)
{
  const int row = blockIdx.x;
  const int t   = threadIdx.x;
  const float* tp = topv + (size_t)row * 10;
  float v0 = tp[0], v1 = tp[1], v2 = tp[2], v3 = tp[3], v4 = tp[4];
  int i0 = __float_as_int(tp[5]);
  int i1 = __float_as_int(tp[6]);
  int i2 = __float_as_int(tp[7]);
  int i3 = __float_as_int(tp[8]);
  int i4 = __float_as_int(tp[9]);
  bool inc4 = (v4 >= v3);
  float e1 = expf(v1 - v0);
  float e2 = expf(v2 - v0);
  float e3 = expf(v3 - v0);
  float e4 = inc4 ? expf(v4 - v0) : 0.0f;
  float inv = 1.0f / (1.0f + e1 + e2 + e3 + e4);
  float w0 = inv, w1 = e1 * inv, w2 = e2 * inv, w3 = e3 * inv, w4 = e4 * inv;

  float* op = out + (size_t)row * NK + t * 16;
  #pragma unroll
  for (int u = 0; u < 4; ++u) {
    v4f o;
    #pragma unroll
    for (int e = 0; e < 4; ++e) {
      int col = t * 16 + u * 4 + e;
      o[e] = (col == i0) ? w0
           : (col == i1) ? w1
           : (col == i2) ? w2
           : (col == i3) ? w3
           : (col == i4) ? w4
           : 0.0f;
    }
    *reinterpret_cast<v4f*>(op + u * 4) = o;
  }
}

extern "C" void kernel_launch(void* const* d_in, const int* in_sizes, int n_in,
                              void* d_out, int out_size, void* d_ws, size_t ws_size,
                              hipStream_t stream) {
  const float* q  = (const float*)d_in[0];
  const float* k  = (const float*)d_in[1];
  const float* Wq = (const float*)d_in[3];
  const float* Wk = (const float*)d_in[4];

  float* qh  = (float*)d_ws;
  float* kh  = qh + (size_t)BATCH * NQ * INNER;
  float* top = kh + (size_t)BATCH * NK * INNER;

  proj_kernel<<<BATCH * NQ / 64, 256, 0, stream>>>(q, Wq, qh, 0.125f);
  proj_kernel<<<BATCH * NK / 64, 256, 0, stream>>>(k, Wk, kh, 1.0f);
  topk_kernel<<<BATCH * (NQ / QT), 256, 0, stream>>>(qh, kh, top);
  scatter_kernel<<<BATCH * NQ, 256, 0, stream>>>(top, (float*)d_out);
}

// Round 4
// 444.331 us; speedup vs baseline: 1.4814x; 1.4814x over previous
//
#include <hip/hip_runtime.h>
#include <hip/hip_bf16.h>
#include <math.h>

typedef float v4f __attribute__((ext_vector_type(4)));

#define BATCH 4
#define NQ 4096
#define NK 4096
#define DIM 256
#define INNER 64
#define NEG_INF (-3.0e38f)

#define QT 32          // q rows per block
#define KC 256         // k cols per staged chunk
#define SKT 260        // khT row stride (floats)
#define SQT 36         // qhT row stride (floats)

// ---------- K1: out[rows,64] = (X[rows,256] @ W[256,64]) * scale -------------
__global__ __launch_bounds__(256) void proj_kernel(
    const float* __restrict__ X, const float* __restrict__ W,
    float* __restrict__ out, float scale)
{
  __shared__ float xs[64 * 260];
  const int t = threadIdx.x;
  const int row0 = blockIdx.x * 64;

  #pragma unroll
  for (int it = 0; it < 16; ++it) {
    int idx = it * 256 + t;
    int r = idx >> 6, dq = idx & 63;
    v4f v = *reinterpret_cast<const v4f*>(X + (size_t)(row0 + r) * DIM + dq * 4);
    *reinterpret_cast<v4f*>(&xs[r * 260 + dq * 4]) = v;
  }
  __syncthreads();

  const int i0 = (t & 15) * 4;
  const int rg = t >> 4;
  float acc[4][4];
  #pragma unroll
  for (int p = 0; p < 4; ++p)
    #pragma unroll
    for (int i = 0; i < 4; ++i) acc[p][i] = 0.f;

  for (int d0 = 0; d0 < DIM; d0 += 4) {
    v4f w0 = *reinterpret_cast<const v4f*>(W + (d0 + 0) * INNER + i0);
    v4f w1 = *reinterpret_cast<const v4f*>(W + (d0 + 1) * INNER + i0);
    v4f w2 = *reinterpret_cast<const v4f*>(W + (d0 + 2) * INNER + i0);
    v4f w3 = *reinterpret_cast<const v4f*>(W + (d0 + 3) * INNER + i0);
    #pragma unroll
    for (int p = 0; p < 4; ++p) {
      v4f x = *reinterpret_cast<const v4f*>(&xs[(rg + 16 * p) * 260 + d0]);
      #pragma unroll
      for (int i = 0; i < 4; ++i) {
        float bs = x[0] * w0[i];
        bs = fmaf(x[1], w1[i], bs);
        bs = fmaf(x[2], w2[i], bs);
        bs = fmaf(x[3], w3[i], bs);
        acc[p][i] += bs;
      }
    }
  }
  #pragma unroll
  for (int p = 0; p < 4; ++p) {
    v4f o;
    #pragma unroll
    for (int i = 0; i < 4; ++i) o[i] = acc[p][i] * scale;
    *reinterpret_cast<v4f*>(out + (size_t)(row0 + rg + 16 * p) * INNER + i0) = o;
  }
}

// ---------- sorted top-5 branchless cascade insert (call only if x > v[4]) ---
__device__ __forceinline__ void insert5(float (&v)[5], int (&ix)[5], float x, int xi) {
  bool g0 = x > v[0], g1 = x > v[1], g2 = x > v[2], g3 = x > v[3];
  v[4]  = g3 ? v[3] : x;                 ix[4] = g3 ? ix[3] : xi;
  v[3]  = g3 ? (g2 ? v[2] : x) : v[3];   ix[3] = g3 ? (g2 ? ix[2] : xi) : ix[3];
  v[2]  = g2 ? (g1 ? v[1] : x) : v[2];   ix[2] = g2 ? (g1 ? ix[1] : xi) : ix[2];
  v[1]  = g1 ? (g0 ? v[0] : x) : v[1];   ix[1] = g1 ? (g0 ? ix[0] : xi) : ix[1];
  v[0]  = g0 ? x : v[0];                 ix[0] = g0 ? xi : ix[0];
}

// ---------- K2: fused scores + per-row top-5 ---------------------------------
// 512 thr = 8 waves; wave qg owns q rows qg*4..+3 (m=4). k-chunk 256 cols
// staged full-dim (round-2 slab, 2-way-free banks). Lane kg owns cols
// 4kg..4kg+3 per chunk (j=4, b128 reads). 2 blocks/CU -> 16 waves/CU.
__global__ __launch_bounds__(512, 4) void topk_kernel(
    const float* __restrict__ qh, const float* __restrict__ kh,
    float* __restrict__ topout)
{
  __shared__ float lds[64 * SKT + 64 * SQT];   // 75776 B
  float* khT = lds;
  float* qhT = lds + 64 * SKT;

  const int t  = threadIdx.x;
  const int b  = blockIdx.x >> 7;              // 128 blocks per batch
  const int q0 = (blockIdx.x & 127) * QT;
  const float* qb = qh + (size_t)b * NQ * INNER;
  const float* kb = kh + (size_t)b * NK * INNER;
  const int qg = t >> 6;                       // wave 0..7
  const int kg = t & 63;                       // lane

  // stage qhT[d][qc]: thread covers (qc = t&31, dg = t>>5), one v4f each
  {
    int qc = t & 31, dg = t >> 5;
    v4f v = *reinterpret_cast<const v4f*>(qb + (size_t)(q0 + qc) * INNER + dg * 4);
    qhT[(dg * 4 + 0) * SQT + qc] = v[0];
    qhT[(dg * 4 + 1) * SQT + qc] = v[1];
    qhT[(dg * 4 + 2) * SQT + qc] = v[2];
    qhT[(dg * 4 + 3) * SQT + qc] = v[3];
  }

  float tv[4][5]; int ti[4][5];
  #pragma unroll
  for (int m = 0; m < 4; ++m)
    #pragma unroll
    for (int j = 0; j < 5; ++j) { tv[m][j] = NEG_INF; ti[m][j] = 0; }

  for (int c = 0; c < NK / KC; ++c) {
    __syncthreads();                           // prev chunk fully consumed
    // stage khT[d][col]: 8 passes x 512 thr cover 256 cols x 16 dim-quads
    #pragma unroll
    for (int pass = 0; pass < 8; ++pass) {
      int col = pass * 32 + (t & 15) + 16 * (t >> 8);
      int dg  = (t >> 4) & 15;
      v4f v = *reinterpret_cast<const v4f*>(
          kb + (size_t)(c * KC + col) * INNER + dg * 4);
      khT[(dg * 4 + 0) * SKT + col] = v[0];
      khT[(dg * 4 + 1) * SKT + col] = v[1];
      khT[(dg * 4 + 2) * SKT + col] = v[2];
      khT[(dg * 4 + 3) * SKT + col] = v[3];
    }
    __syncthreads();

    float acc[4][4];
    #pragma unroll
    for (int m = 0; m < 4; ++m)
      #pragma unroll
      for (int j = 0; j < 4; ++j) acc[m][j] = 0.f;

    #pragma unroll 2
    for (int dd = 0; dd < 64; dd += 4) {
      v4f kv[4], qa[4];
      #pragma unroll
      for (int s = 0; s < 4; ++s) {
        kv[s] = *reinterpret_cast<const v4f*>(&khT[(dd + s) * SKT + kg * 4]);
        qa[s] = *reinterpret_cast<const v4f*>(&qhT[(dd + s) * SQT + qg * 4]);
      }
      #pragma unroll
      for (int m = 0; m < 4; ++m) {
        float q0v = qa[0][m], q1v = qa[1][m], q2v = qa[2][m], q3v = qa[3][m];
        #pragma unroll
        for (int j = 0; j < 4; ++j) {
          float bs = q0v * kv[0][j];           // same blocked order as round 2
          bs = fmaf(q1v, kv[1][j], bs);
          bs = fmaf(q2v, kv[2][j], bs);
          bs = fmaf(q3v, kv[3][j], bs);
          acc[m][j] += bs;
        }
      }
    }

    const int kbase = c * KC + 4 * kg;
    #pragma unroll
    for (int m = 0; m < 4; ++m) {
      float mx = fmaxf(fmaxf(acc[m][0], acc[m][1]), fmaxf(acc[m][2], acc[m][3]));
      if (mx > tv[m][4]) {
        #pragma unroll
        for (int j = 0; j < 4; ++j) {
          float x = acc[m][j];
          if (x > tv[m][4]) insert5(tv[m], ti[m], x, kbase + j);
        }
      }
    }
  }

  // full 64-lane butterfly merge; lane 0 of each wave has its rows' results
  #pragma unroll
  for (int s = 1; s <= 32; s <<= 1) {
    #pragma unroll
    for (int m = 0; m < 4; ++m) {
      float bv[5]; int bi[5];
      #pragma unroll
      for (int j = 0; j < 5; ++j) {
        bv[j] = __shfl_xor(tv[m][j], s, 64);
        bi[j] = __shfl_xor(ti[m][j], s, 64);
      }
      #pragma unroll
      for (int j = 0; j < 5; ++j)
        if (bv[j] > tv[m][4]) insert5(tv[m], ti[m], bv[j], bi[j]);
    }
  }

  if (kg == 0) {
    #pragma unroll
    for (int m = 0; m < 4; ++m) {
      size_t rowg = (size_t)b * NQ + q0 + qg * 4 + m;
      #pragma unroll
      for (int j = 0; j < 5; ++j) {
        topout[rowg * 10 + j]     = tv[m][j];
        topout[rowg * 10 + 5 + j] = __int_as_float(ti[m][j]);
      }
    }
  }
}

// ---------- K3: fused zero-fill + softmax-of-survivors scatter (f32 out) -----
__global__ __launch_bounds__(256) void scatter_kernel(
    const float* __restrict__ topv, float* __restrict__ out)
{
  const int row = blockIdx.x;
  const int t   = threadIdx.x;
  const float* tp = topv + (size_t)row * 10;
  float v0 = tp[0], v1 = tp[1], v2 = tp[2], v3 = tp[3], v4 = tp[4];
  int i0 = __float_as_int(tp[5]);
  int i1 = __float_as_int(tp[6]);
  int i2 = __float_as_int(tp[7]);
  int i3 = __float_as_int(tp[8]);
  int i4 = __float_as_int(tp[9]);
  bool inc4 = (v4 >= v3);                      // tie at threshold -> 5 survive
  float e1 = expf(v1 - v0);
  float e2 = expf(v2 - v0);
  float e3 = expf(v3 - v0);
  float e4 = inc4 ? expf(v4 - v0) : 0.0f;
  float inv = 1.0f / (1.0f + e1 + e2 + e3 + e4);
  float w0 = inv, w1 = e1 * inv, w2 = e2 * inv, w3 = e3 * inv, w4 = e4 * inv;

  float* op = out + (size_t)row * NK + t * 16;
  #pragma unroll
  for (int u = 0; u < 4; ++u) {
    v4f o;
    #pragma unroll
    for (int e = 0; e < 4; ++e) {
      int col = t * 16 + u * 4 + e;
      o[e] = (col == i0) ? w0
           : (col == i1) ? w1
           : (col == i2) ? w2
           : (col == i3) ? w3
           : (col == i4) ? w4
           : 0.0f;
    }
    *reinterpret_cast<v4f*>(op + u * 4) = o;
  }
}

extern "C" void kernel_launch(void* const* d_in, const int* in_sizes, int n_in,
                              void* d_out, int out_size, void* d_ws, size_t ws_size,
                              hipStream_t stream) {
  const float* q  = (const float*)d_in[0];
  const float* k  = (const float*)d_in[1];
  const float* Wq = (const float*)d_in[3];
  const float* Wk = (const float*)d_in[4];

  float* qh  = (float*)d_ws;
  float* kh  = qh + (size_t)BATCH * NQ * INNER;
  float* top = kh + (size_t)BATCH * NK * INNER;

  proj_kernel<<<BATCH * NQ / 64, 256, 0, stream>>>(q, Wq, qh, 0.125f);
  proj_kernel<<<BATCH * NK / 64, 256, 0, stream>>>(k, Wk, kh, 1.0f);
  topk_kernel<<<BATCH * (NQ / QT), 512, 0, stream>>>(qh, kh, top);
  scatter_kernel<<<BATCH * NQ, 256, 0, stream>>>(top, (float*)d_out);
}